// Round 6
// baseline (269.091 us; speedup 1.0000x reference)
//
#include <hip/hip_runtime.h>

// DerivativeNet direction='x': B=16,C=2,H=1024,W=1024 fp32.
// Two rows per block (6 float4 loads in flight per wave = 2x bytes-in-flight
// vs R5), 8192 blocks = 4x oversubscription so the CP refills CUs (fixes
// R4's tail). Ballot/mbcnt mask algebra; LDS carries only the 8 per-wave
// mask counts (32 B), lgkmcnt-only barrier (u loads NOT drained across it).
// Wave-boundary halos via 2-lane global loads (L2 hits).
// __launch_bounds__(256,6): VGPR cap 85 so the 24 payload regs stay resident
// (R1/R2's failure mode was the allocator clamping at 44-52 and serializing).

typedef float v4f __attribute__((ext_vector_type(4)));

__device__ __forceinline__ int prefix_below(unsigned long long m) {
    // popcount of m over lanes strictly below this lane
    return (int)__builtin_amdgcn_mbcnt_hi(
        (unsigned)(m >> 32),
        __builtin_amdgcn_mbcnt_lo((unsigned)(m & 0xffffffffull), 0u));
}

__global__ __launch_bounds__(256, 6) void deriv_x_kernel(
    const float* __restrict__ u,
    const float* __restrict__ mask,
    float* __restrict__ out)
{
    const int tid  = threadIdx.x;        // owns elements 4tid..4tid+3 of each row
    const int lane = tid & 63;
    const int wave = tid >> 6;
    const int rowA = blockIdx.x << 1;    // even row; rowB = rowA+1, same image
    const int b    = rowA >> 10;
    const int yA   = rowA & 1023;

    const size_t moffA  = (size_t)rowA << 10;                    // mask[b,0,yA,:]
    const size_t moffB  = moffA + 1024;
    const size_t u0offA = ((size_t)b << 21) + ((size_t)yA << 10);// u[b,0,yA,:]
    const size_t u0offB = u0offA + 1024;
    const size_t u1offA = u0offA + (size_t)(1 << 20);            // u[b,1,yA,:]
    const size_t u1offB = u1offA + 1024;

    // ---- 6 main float4 loads up-front: masks first (they gate the barrier path)
    const float4 mA = ((const float4*)(mask + moffA))[tid];
    const float4 mB = ((const float4*)(mask + moffB))[tid];
    const float4 aA = ((const float4*)(u + u0offA))[tid];
    const float4 aB = ((const float4*)(u + u0offB))[tid];
    const float4 cA = ((const float4*)(u + u1offA))[tid];
    const float4 cB = ((const float4*)(u + u1offB))[tid];

    // ---- wave-boundary halo loads (2 active lanes/wave/row, L2-resident lines)
    float blmA=0.f, bl0A=0.f, bl1A=0.f, brmA=0.f, br0A=0.f, br1A=0.f;
    float blmB=0.f, bl0B=0.f, bl1B=0.f, brmB=0.f, br0B=0.f, br1B=0.f;
    if (lane == 0 && wave > 0) {
        const int e = (wave << 8) - 1;
        blmA = mask[moffA + e]; bl0A = u[u0offA + e]; bl1A = u[u1offA + e];
        blmB = mask[moffB + e]; bl0B = u[u0offB + e]; bl1B = u[u1offB + e];
    }
    if (lane == 63 && wave < 3) {
        const int e = (wave << 8) + 256;
        brmA = mask[moffA + e]; br0A = u[u0offA + e]; br1A = u[u1offA + e];
        brmB = mask[moffB + e]; br0B = u[u0offB + e]; br1B = u[u1offB + e];
    }

    // ---- ballots per row (uniform 64-bit masks in SGPRs)
#define BALLOTS(S)                                                                  \
    const int i0##S = (m##S.x != 0.f), i1##S = (m##S.y != 0.f);                     \
    const int i2##S = (m##S.z != 0.f), i3##S = (m##S.w != 0.f);                     \
    const unsigned long long B0##S = __ballot(i0##S);                               \
    const unsigned long long B1##S = __ballot(i1##S);                               \
    const unsigned long long B2##S = __ballot(i2##S);                               \
    const unsigned long long B3##S = __ballot(i3##S);                               \
    const int wtot##S = __popcll(B0##S) + __popcll(B1##S) +                         \
                        __popcll(B2##S) + __popcll(B3##S);

    BALLOTS(A)
    BALLOTS(B)
#undef BALLOTS

    // ---- cross-wave glue: 8 per-wave mask counts (32 B of LDS), adjacent so
    //      lane0's two writes can merge into one ds_write_b64
    __shared__ int s_tot[4][2];
    if (lane == 0) { s_tot[wave][0] = wtotA; s_tot[wave][1] = wtotB; }

    // lgkmcnt-only barrier: ds_write visible, u loads NOT drained
    asm volatile("s_waitcnt lgkmcnt(0)" ::: "memory");
    __builtin_amdgcn_s_barrier();
    asm volatile("" ::: "memory");       // compiler fence: no LDS-read hoisting

    const float inv2h = 50.0f;    // 1/(2h), h=0.01
    const float invh  = 100.0f;   // 1/h

#define DO_CH(V, BL, BR, OFF)                                                      \
    {                                                                              \
        float ul = __shfl_up(V.w, 1);                                              \
        if (lane == 0) ul = BL;    /* wave0: BL=0 == zero-pad */                   \
        float ur = __shfl_down(V.x, 1);                                            \
        if (lane == 63) ur = BR;   /* wave3: BR=0 == zero-pad */                   \
        v4f o;                                                                     \
        o.x = er0*((V.y - ul )*inv2h) + e10*((V.y - V.x)*invh) + e20*((V.x - ul )*invh); \
        o.y = er1*((V.z - V.x)*inv2h) + e11*((V.z - V.y)*invh) + e21*((V.y - V.x)*invh); \
        o.z = er2*((V.w - V.y)*inv2h) + e12*((V.w - V.z)*invh) + e22*((V.z - V.y)*invh); \
        o.w = er3*((ur  - V.z)*inv2h) + e13*((ur  - V.w)*invh) + e23*((V.w - V.z)*invh); \
        ((v4f*)(out + OFF))[tid] = o;                                              \
    }

#define ROW_OUT(S, RI, U0OFF, U1OFF)                                               \
    {                                                                              \
        const int t0 = s_tot[0][RI], t1 = s_tot[1][RI];                            \
        const int t2 = s_tot[2][RI], t3 = s_tot[3][RI];                            \
        const int total = t0 + t1 + t2 + t3;                                       \
        int base = 0;                                                              \
        if (wave > 0) base += t0;                                                  \
        if (wave > 1) base += t1;                                                  \
        if (wave > 2) base += t2;                                                  \
        /* eroded 3-box via 64-bit mask algebra (boundary lanes fixed below) */    \
        const unsigned long long E0 = (B3##S << 1) & B0##S & B1##S;                \
        const unsigned long long E1 = B0##S & B1##S & B2##S;                       \
        const unsigned long long E2 = B1##S & B2##S & B3##S;                       \
        const unsigned long long E3 = B2##S & B3##S & (B0##S >> 1);                \
        float er0 = ((E0 >> lane) & 1ull) ? 1.f : 0.f;                             \
        const float er1 = ((E1 >> lane) & 1ull) ? 1.f : 0.f;                       \
        const float er2 = ((E2 >> lane) & 1ull) ? 1.f : 0.f;                       \
        float er3 = ((E3 >> lane) & 1ull) ? 1.f : 0.f;                             \
        if (lane == 0)  er0 = (blm##S != 0.f && i0##S && i1##S) ? 1.f : 0.f;       \
        if (lane == 63) er3 = (i2##S && i3##S && brm##S != 0.f) ? 1.f : 0.f;       \
        /* inclusive cumsum at the 4 owned elements (exact integer) */             \
        const int excl = base + prefix_below(B0##S) + prefix_below(B1##S) +        \
                                prefix_below(B2##S) + prefix_below(B3##S);         \
        const int cs0 = excl + i0##S;                                              \
        const int cs1 = cs0 + i1##S;                                               \
        const int cs2 = cs1 + i2##S;                                               \
        const int cs3 = cs2 + i3##S;                                               \
        const float e10 = (cs0 == 1) ? 1.f : 0.f;                                  \
        const float e11 = (cs1 == 1) ? 1.f : 0.f;                                  \
        const float e12 = (cs2 == 1) ? 1.f : 0.f;                                  \
        const float e13 = (cs3 == 1) ? 1.f : 0.f;                                  \
        const float e20 = (i0##S && cs0 == total) ? 1.f : 0.f;                     \
        const float e21 = (i1##S && cs1 == total) ? 1.f : 0.f;                     \
        const float e22 = (i2##S && cs2 == total) ? 1.f : 0.f;                     \
        const float e23 = (i3##S && cs3 == total) ? 1.f : 0.f;                     \
        DO_CH(a##S, bl0##S, br0##S, U0OFF)                                         \
        DO_CH(c##S, bl1##S, br1##S, U1OFF)                                         \
    }

    ROW_OUT(A, 0, u0offA, u1offA)
    ROW_OUT(B, 1, u0offB, u1offB)
#undef ROW_OUT
#undef DO_CH
}

extern "C" void kernel_launch(void* const* d_in, const int* in_sizes, int n_in,
                              void* d_out, int out_size, void* d_ws, size_t ws_size,
                              hipStream_t stream) {
    const float* u    = (const float*)d_in[0];
    const float* mask = (const float*)d_in[1];
    float* out        = (float*)d_out;
    // 16384 rows / 2 rows per block = 8192 blocks, 256 threads each
    deriv_x_kernel<<<dim3(8192), dim3(256), 0, stream>>>(u, mask, out);
}